// Round 1
// baseline (3144.127 us; speedup 1.0000x reference)
//
#include <hip/hip_runtime.h>
#include <math.h>

// Model dims
#define Bdim 32
#define CIN 8
#define CMID 128
#define COUT 128
#define Ldim 512
#define Tsteps 50
#define DTc 0.5f
#define Kdim 26

// y_seq strides (floats)
#define Y_BSTRIDE (50*128*512)   // 3276800
#define Y_TSTRIDE (128*512)      // 65536

// -------------------- weight transpose: w[co][ci][k] -> wt[(ci*3+k)][co] -----
__global__ void wtrans_k(const float* __restrict__ w, float* __restrict__ wt, int cin) {
    int idx = blockIdx.x * blockDim.x + threadIdx.x;
    int total = cin * 3 * 128;
    if (idx >= total) return;
    int row = idx >> 7;          // ci*3+k
    int co  = idx & 127;
    int ci = row / 3, k = row - ci * 3;
    wt[idx] = w[(co * cin + ci) * 3 + k];
}

// -------------------- conv1d, C_in = 8, zero pad, ReLU ----------------------
__global__ __launch_bounds__(256) void conv8_k(
    const float* __restrict__ src, int sbs,
    float* __restrict__ dst, int dbs,
    const float* __restrict__ wt, const float* __restrict__ bias)
{
    int b = blockIdx.y, tile = blockIdx.x, tid = threadIdx.x;
    int l0 = tile * 64;
    int tl4 = (tid & 15) * 4;
    int co0 = (tid >> 4) * 8;
    __shared__ float xs[8 * 68];
    __shared__ float wsh[24 * 128];
    const float* sb = src + (size_t)b * sbs;
    for (int idx = tid; idx < 8 * 66; idx += 256) {
        int ci = idx / 66, ll = idx - ci * 66;
        int gl = l0 - 1 + ll;
        xs[ci * 68 + ll] = (gl >= 0 && gl < 512) ? sb[ci * 512 + gl] : 0.f;
    }
    for (int idx = tid; idx < 24 * 128; idx += 256) wsh[idx] = wt[idx];
    __syncthreads();
    float acc[8][4] = {};
    #pragma unroll
    for (int ci = 0; ci < 8; ++ci) {
        float x6[6];
        #pragma unroll
        for (int j = 0; j < 6; ++j) x6[j] = xs[ci * 68 + tl4 + j];
        #pragma unroll
        for (int k = 0; k < 3; ++k) {
            float w8[8];
            #pragma unroll
            for (int i = 0; i < 8; ++i) w8[i] = wsh[(ci * 3 + k) * 128 + co0 + i];
            #pragma unroll
            for (int i = 0; i < 8; ++i)
                #pragma unroll
                for (int j = 0; j < 4; ++j)
                    acc[i][j] = fmaf(w8[i], x6[k + j], acc[i][j]);
        }
    }
    #pragma unroll
    for (int i = 0; i < 8; ++i) {
        int co = co0 + i;
        float bv = bias[co];
        float4 o;
        o.x = fmaxf(acc[i][0] + bv, 0.f);
        o.y = fmaxf(acc[i][1] + bv, 0.f);
        o.z = fmaxf(acc[i][2] + bv, 0.f);
        o.w = fmaxf(acc[i][3] + bv, 0.f);
        *(float4*)(dst + (size_t)b * dbs + (size_t)co * 512 + l0 + tl4) = o;
    }
}

// -------------------- conv1d, C_in = 128, zero pad, act (1=relu,2=tanh) -----
__global__ __launch_bounds__(256) void conv128_k(
    const float* __restrict__ src, int sbs,
    float* __restrict__ dst, int dbs,
    const float* __restrict__ wt, const float* __restrict__ bias, int act)
{
    int b = blockIdx.y, tile = blockIdx.x, tid = threadIdx.x;
    int l0 = tile * 64;
    int tl4 = (tid & 15) * 4;
    int co0 = (tid >> 4) * 8;
    __shared__ float xs[32 * 68];
    __shared__ float wsh[96 * 128];
    const float* sb = src + (size_t)b * sbs;
    float acc[8][4] = {};
    for (int chunk = 0; chunk < 4; ++chunk) {
        for (int idx = tid; idx < 32 * 66; idx += 256) {
            int ci = idx / 66, ll = idx - ci * 66;
            int gl = l0 - 1 + ll;
            xs[ci * 68 + ll] = (gl >= 0 && gl < 512) ? sb[(chunk * 32 + ci) * 512 + gl] : 0.f;
        }
        {
            const float4* wsrc = (const float4*)(wt + chunk * 96 * 128);
            float4* wdst = (float4*)wsh;
            for (int idx = tid; idx < 96 * 128 / 4; idx += 256) wdst[idx] = wsrc[idx];
        }
        __syncthreads();
        #pragma unroll 4
        for (int ci = 0; ci < 32; ++ci) {
            float x6[6];
            #pragma unroll
            for (int j = 0; j < 6; ++j) x6[j] = xs[ci * 68 + tl4 + j];
            #pragma unroll
            for (int k = 0; k < 3; ++k) {
                float w8[8];
                #pragma unroll
                for (int i = 0; i < 8; ++i) w8[i] = wsh[(ci * 3 + k) * 128 + co0 + i];
                #pragma unroll
                for (int i = 0; i < 8; ++i)
                    #pragma unroll
                    for (int j = 0; j < 4; ++j)
                        acc[i][j] = fmaf(w8[i], x6[k + j], acc[i][j]);
            }
        }
        __syncthreads();
    }
    #pragma unroll
    for (int i = 0; i < 8; ++i) {
        int co = co0 + i;
        float bv = bias[co];
        float v[4];
        #pragma unroll
        for (int j = 0; j < 4; ++j) {
            float t = acc[i][j] + bv;
            if (act == 1) t = fmaxf(t, 0.f);
            else if (act == 2) t = tanhf(t);
            v[j] = t;
        }
        *(float4*)(dst + (size_t)b * dbs + (size_t)co * 512 + l0 + tl4) =
            make_float4(v[0], v[1], v[2], v[3]);
    }
}

// -------------------- recurrent step: spring conv (circular) + update -------
__global__ __launch_bounds__(256) void recur_k(
    const float* __restrict__ src, int sbs,        // hy_{t-1}
    const float* __restrict__ omega, const float* __restrict__ alpha,
    float* __restrict__ hz, float* __restrict__ yout,
    float* __restrict__ part, const float* __restrict__ wyt, int t)
{
    int b = blockIdx.y, tile = blockIdx.x, tid = threadIdx.x;
    int l0 = tile * 64;
    int tl4 = (tid & 15) * 4;
    int co0 = (tid >> 4) * 8;
    __shared__ float xs[32 * 68];
    __shared__ float wsh[96 * 128];
    const float* sb = src + (size_t)b * sbs;
    float acc[8][4] = {};
    for (int chunk = 0; chunk < 4; ++chunk) {
        for (int idx = tid; idx < 32 * 66; idx += 256) {
            int ci = idx / 66, ll = idx - ci * 66;
            int gl = (l0 - 1 + ll + 512) & 511;      // circular
            xs[ci * 68 + ll] = sb[(chunk * 32 + ci) * 512 + gl];
        }
        {
            const float4* wsrc = (const float4*)(wyt + chunk * 96 * 128);
            float4* wdst = (float4*)wsh;
            for (int idx = tid; idx < 96 * 128 / 4; idx += 256) wdst[idx] = wsrc[idx];
        }
        __syncthreads();
        #pragma unroll 4
        for (int ci = 0; ci < 32; ++ci) {
            float x6[6];
            #pragma unroll
            for (int j = 0; j < 6; ++j) x6[j] = xs[ci * 68 + tl4 + j];
            #pragma unroll
            for (int k = 0; k < 3; ++k) {
                float w8[8];
                #pragma unroll
                for (int i = 0; i < 8; ++i) w8[i] = wsh[(ci * 3 + k) * 128 + co0 + i];
                #pragma unroll
                for (int i = 0; i < 8; ++i)
                    #pragma unroll
                    for (int j = 0; j < 4; ++j)
                        acc[i][j] = fmaf(w8[i], x6[k + j], acc[i][j]);
            }
        }
        __syncthreads();
    }
    // fused update + y write + ybar partials
    #pragma unroll
    for (int i = 0; i < 8; ++i) {
        int co = co0 + i;
        size_t off = ((size_t)b * 128 + co) * 512 + l0 + tl4;
        float4 om = *(const float4*)(omega + off);
        float4 al = *(const float4*)(alpha + off);
        float4 hyv = *(const float4*)(sb + (size_t)co * 512 + l0 + tl4);
        float4 hzv;
        if (t == 0) hzv = make_float4(0.f, 0.f, 0.f, 0.f);
        else        hzv = *(const float4*)(hz + off);
        float so[4], hzn[4], hyn[4];
        float accv[4] = {acc[i][0], acc[i][1], acc[i][2], acc[i][3]};
        float omv[4] = {om.x, om.y, om.z, om.w};
        float alv[4] = {al.x, al.y, al.z, al.w};
        float hyvv[4] = {hyv.x, hyv.y, hyv.z, hyv.w};
        float hzvv[4] = {hzv.x, hzv.y, hzv.z, hzv.w};
        float lsum = 0.f;
        #pragma unroll
        for (int j = 0; j < 4; ++j) {
            so[j] = tanhf(accv[j]);
            hzn[j] = hzvv[j] + DTc * (so[j] - omv[j] * hyvv[j] - alv[j] * hzvv[j]);
            hyn[j] = hyvv[j] + DTc * hzn[j];
            lsum += hyn[j];
        }
        *(float4*)(hz + off) = make_float4(hzn[0], hzn[1], hzn[2], hzn[3]);
        *(float4*)(yout + (size_t)b * Y_BSTRIDE + (size_t)t * Y_TSTRIDE
                   + (size_t)co * 512 + l0 + tl4) =
            make_float4(hyn[0], hyn[1], hyn[2], hyn[3]);
        // reduce lsum over the 16 l-groups (lanes sharing tc_g are 16 consecutive lanes)
        #pragma unroll
        for (int d = 1; d < 16; d <<= 1) lsum += __shfl_xor(lsum, d);
        if ((tid & 15) == 0)
            part[(((size_t)b * 50 + t) * 128 + co) * 8 + tile] = lsum;
    }
}

// -------------------- readout ----------------------------------------------
__global__ __launch_bounds__(256) void readout_k(
    const float* __restrict__ part, const float* __restrict__ fct,
    const float* __restrict__ rw1, const float* __restrict__ rb1,
    const float* __restrict__ rw2, const float* __restrict__ rb2,
    const float* __restrict__ rw3, const float* __restrict__ rb3,
    float* __restrict__ out)
{
    int b = blockIdx.x, tid = threadIdx.x;
    __shared__ float ybar[50 * 128];
    __shared__ float feat[26 * 128];
    __shared__ float h1[64];
    __shared__ float h2[32];
    for (int idx = tid; idx < 50 * 128; idx += 256) {
        const float* p = part + ((size_t)b * 6400 + idx) * 8;
        float s = 0.f;
        #pragma unroll
        for (int q = 0; q < 8; ++q) s += p[q];
        ybar[idx] = s * (1.f / 512.f);
    }
    __syncthreads();
    for (int idx = tid; idx < 26 * 128; idx += 256) {
        int k = idx >> 7, c = idx & 127;
        float s = 0.f;
        for (int t = 0; t < 50; ++t) s += fct[k * 50 + t] * ybar[t * 128 + c];
        feat[idx] = s;
    }
    __syncthreads();
    {
        int j = tid >> 2, q = tid & 3;
        float s = 0.f;
        const float* r = rw1 + (size_t)j * 3328 + q * 832;
        const float* f = feat + q * 832;
        for (int i = 0; i < 832; ++i) s += f[i] * r[i];
        s += __shfl_xor(s, 1);
        s += __shfl_xor(s, 2);
        if (q == 0) h1[j] = fmaxf(s + rb1[j], 0.f);
    }
    __syncthreads();
    if (tid < 32) {
        float s = 0.f;
        for (int i = 0; i < 64; ++i) s += h1[i] * rw2[tid * 64 + i];
        h2[tid] = fmaxf(s + rb2[tid], 0.f);
    }
    __syncthreads();
    if (tid == 0) {
        float s = 0.f;
        for (int i = 0; i < 32; ++i) s += h2[i] * rw3[i];
        out[b] = s + rb3[0];
    }
}

// -------------------- launch ------------------------------------------------
extern "C" void kernel_launch(void* const* d_in, const int* in_sizes, int n_in,
                              void* d_out, int out_size, void* d_ws, size_t ws_size,
                              hipStream_t stream)
{
    const float* x   = (const float*)d_in[0];
    const float* ow1 = (const float*)d_in[1];  const float* ob1 = (const float*)d_in[2];
    const float* ow2 = (const float*)d_in[3];  const float* ob2 = (const float*)d_in[4];
    const float* ow3 = (const float*)d_in[5];  const float* ob3 = (const float*)d_in[6];
    const float* aw1 = (const float*)d_in[7];  const float* ab1 = (const float*)d_in[8];
    const float* aw2 = (const float*)d_in[9];  const float* ab2 = (const float*)d_in[10];
    const float* aw3 = (const float*)d_in[11]; const float* ab3 = (const float*)d_in[12];
    const float* hw1 = (const float*)d_in[13]; const float* hb1 = (const float*)d_in[14];
    const float* hw2 = (const float*)d_in[15]; const float* hb2 = (const float*)d_in[16];
    const float* hw3 = (const float*)d_in[17]; const float* hb3 = (const float*)d_in[18];
    const float* hw4 = (const float*)d_in[19]; const float* hb4 = (const float*)d_in[20];
    const float* wy  = (const float*)d_in[21];
    const float* fct = (const float*)d_in[22];
    const float* rw1 = (const float*)d_in[23]; const float* rb1 = (const float*)d_in[24];
    const float* rw2 = (const float*)d_in[25]; const float* rb2 = (const float*)d_in[26];
    const float* rw3 = (const float*)d_in[27]; const float* rb3 = (const float*)d_in[28];

    float* out  = (float*)d_out;
    float* yout = out + 32;                       // y_seq region
    float* ws   = (float*)d_ws;

    // ws layout (floats)
    float* OMEGA = ws;                            // 2097152
    float* ALPHA = ws + 2097152;                  // 2097152
    float* HZ    = ws + 4194304;                  // 2097152
    float* WT    = ws + 6291456;                  // 402432
    float* PART  = ws + 6693888;                  // 1638400  (total ~33.3 MB)

    // scratch buffers living inside the y_seq output region (overwritten later
    // by steps 48/49, long after their last use during the encoder phase)
    float* TMP1 = yout + 49 * Y_TSTRIDE;          // bstride Y_BSTRIDE
    float* HY0  = yout + 48 * Y_TSTRIDE;          // bstride Y_BSTRIDE

    // wt sub-offsets
    float* OW1T = WT + 0;      float* AW1T = WT + 3072;   float* HW1T = WT + 6144;
    float* OW2T = WT + 9216;   float* OW3T = WT + 58368;
    float* AW2T = WT + 107520; float* AW3T = WT + 156672;
    float* HW2T = WT + 205824; float* HW3T = WT + 254976; float* HW4T = WT + 304128;
    float* WYT  = WT + 353280;

    // weight transposes
    wtrans_k<<<12, 256, 0, stream>>>(ow1, OW1T, 8);
    wtrans_k<<<12, 256, 0, stream>>>(aw1, AW1T, 8);
    wtrans_k<<<12, 256, 0, stream>>>(hw1, HW1T, 8);
    wtrans_k<<<192, 256, 0, stream>>>(ow2, OW2T, 128);
    wtrans_k<<<192, 256, 0, stream>>>(ow3, OW3T, 128);
    wtrans_k<<<192, 256, 0, stream>>>(aw2, AW2T, 128);
    wtrans_k<<<192, 256, 0, stream>>>(aw3, AW3T, 128);
    wtrans_k<<<192, 256, 0, stream>>>(hw2, HW2T, 128);
    wtrans_k<<<192, 256, 0, stream>>>(hw3, HW3T, 128);
    wtrans_k<<<192, 256, 0, stream>>>(hw4, HW4T, 128);
    wtrans_k<<<192, 256, 0, stream>>>(wy,  WYT, 128);

    dim3 grid(8, 32);

    // omega encoder: x -> TMP1 -> HZ -> OMEGA
    conv8_k  <<<grid, 256, 0, stream>>>(x, 8 * 512, TMP1, Y_BSTRIDE, OW1T, ob1);
    conv128_k<<<grid, 256, 0, stream>>>(TMP1, Y_BSTRIDE, HZ, 128 * 512, OW2T, ob2, 1);
    conv128_k<<<grid, 256, 0, stream>>>(HZ, 128 * 512, OMEGA, 128 * 512, OW3T, ob3, 1);
    // alpha encoder
    conv8_k  <<<grid, 256, 0, stream>>>(x, 8 * 512, TMP1, Y_BSTRIDE, AW1T, ab1);
    conv128_k<<<grid, 256, 0, stream>>>(TMP1, Y_BSTRIDE, HZ, 128 * 512, AW2T, ab2, 1);
    conv128_k<<<grid, 256, 0, stream>>>(HZ, 128 * 512, ALPHA, 128 * 512, AW3T, ab3, 1);
    // hy encoder: x -> TMP1 -> HZ -> TMP1 -> HY0 (tanh)
    conv8_k  <<<grid, 256, 0, stream>>>(x, 8 * 512, TMP1, Y_BSTRIDE, HW1T, hb1);
    conv128_k<<<grid, 256, 0, stream>>>(TMP1, Y_BSTRIDE, HZ, 128 * 512, HW2T, hb2, 1);
    conv128_k<<<grid, 256, 0, stream>>>(HZ, 128 * 512, TMP1, Y_BSTRIDE, HW3T, hb3, 1);
    conv128_k<<<grid, 256, 0, stream>>>(TMP1, Y_BSTRIDE, HY0, Y_BSTRIDE, HW4T, hb4, 2);

    // recurrence: state lives in the y_seq region of d_out
    for (int t = 0; t < Tsteps; ++t) {
        const float* src = (t == 0) ? HY0 : (yout + (size_t)(t - 1) * Y_TSTRIDE);
        int sbs = (t == 0) ? Y_BSTRIDE : Y_BSTRIDE;   // both live in y-layout
        recur_k<<<grid, 256, 0, stream>>>(src, sbs, OMEGA, ALPHA, HZ, yout, PART, WYT, t);
    }

    // readout
    readout_k<<<32, 256, 0, stream>>>(PART, fct, rw1, rb1, rw2, rb2, rw3, rb3, out);
}

// Round 2
// 1498.231 us; speedup vs baseline: 2.0986x; 2.0986x over previous
//
#include <hip/hip_runtime.h>
#include <hip/hip_bf16.h>
#include <math.h>

// Model dims
#define Bdim 32
#define Ldim 512
#define Tsteps 50
#define DTc 0.5f

// y_seq strides (floats)
#define YB (50*128*512)   // 3276800
#define YT (128*512)      // 65536

typedef __attribute__((ext_vector_type(8))) short bf16x8;   // 8 bf16 = 4 VGPR
typedef __attribute__((ext_vector_type(4))) float f32x4;

__device__ __forceinline__ unsigned short f2bf(float f) {
    unsigned int u = __builtin_bit_cast(unsigned int, f);
    u += 0x7fffu + ((u >> 16) & 1u);          // RNE
    return (unsigned short)(u >> 16);
}

__device__ __forceinline__ float tanh_fast(float x) {
    float ax = fabsf(x);
    float e  = __expf(-2.f * ax);
    float r  = (1.f - e) * __builtin_amdgcn_rcpf(1.f + e);
    return __builtin_copysignf(r, x);
}

// -------------------- weight transpose (fp32 encoders): w[co][ci][k] -> wt[(ci*3+k)][co]
__global__ void wtrans_k(const float* __restrict__ w, float* __restrict__ wt, int cin) {
    int idx = blockIdx.x * blockDim.x + threadIdx.x;
    int total = cin * 3 * 128;
    if (idx >= total) return;
    int row = idx >> 7;          // ci*3+k
    int co  = idx & 127;
    int ci = row / 3, k = row - ci * 3;
    wt[idx] = w[(co * cin + ci) * 3 + k];
}

// -------------------- recur weight prep: w2 bf16 [co][kappa=384], kappa=(s*32+u), k=s>>2, ci=(s&3)*32+u
__global__ void wprep_k(const float* __restrict__ wy, unsigned short* __restrict__ w2) {
    int idx = blockIdx.x * 256 + threadIdx.x;
    if (idx >= 128 * 384) return;
    int co = idx / 384, kap = idx - co * 384;
    int k = kap >> 7;
    int ci = ((kap >> 5) & 3) * 32 + (kap & 31);
    w2[idx] = f2bf(wy[(co * 128 + ci) * 3 + k]);
}

// -------------------- conv1d, C_in = 8, zero pad, ReLU ----------------------
__global__ __launch_bounds__(256) void conv8_k(
    const float* __restrict__ src, int sbs,
    float* __restrict__ dst, int dbs,
    const float* __restrict__ wt, const float* __restrict__ bias)
{
    int b = blockIdx.y, tile = blockIdx.x, tid = threadIdx.x;
    int l0 = tile * 64;
    int tl4 = (tid & 15) * 4;
    int co0 = (tid >> 4) * 8;
    __shared__ float xs[8 * 68];
    __shared__ float wsh[24 * 128];
    const float* sb = src + (size_t)b * sbs;
    for (int idx = tid; idx < 8 * 66; idx += 256) {
        int ci = idx / 66, ll = idx - ci * 66;
        int gl = l0 - 1 + ll;
        xs[ci * 68 + ll] = (gl >= 0 && gl < 512) ? sb[ci * 512 + gl] : 0.f;
    }
    for (int idx = tid; idx < 24 * 128; idx += 256) wsh[idx] = wt[idx];
    __syncthreads();
    float acc[8][4] = {};
    #pragma unroll
    for (int ci = 0; ci < 8; ++ci) {
        float x6[6];
        #pragma unroll
        for (int j = 0; j < 6; ++j) x6[j] = xs[ci * 68 + tl4 + j];
        #pragma unroll
        for (int k = 0; k < 3; ++k) {
            float w8[8];
            #pragma unroll
            for (int i = 0; i < 8; ++i) w8[i] = wsh[(ci * 3 + k) * 128 + co0 + i];
            #pragma unroll
            for (int i = 0; i < 8; ++i)
                #pragma unroll
                for (int j = 0; j < 4; ++j)
                    acc[i][j] = fmaf(w8[i], x6[k + j], acc[i][j]);
        }
    }
    #pragma unroll
    for (int i = 0; i < 8; ++i) {
        int co = co0 + i;
        float bv = bias[co];
        float4 o;
        o.x = fmaxf(acc[i][0] + bv, 0.f);
        o.y = fmaxf(acc[i][1] + bv, 0.f);
        o.z = fmaxf(acc[i][2] + bv, 0.f);
        o.w = fmaxf(acc[i][3] + bv, 0.f);
        *(float4*)(dst + (size_t)b * dbs + (size_t)co * 512 + l0 + tl4) = o;
    }
}

// -------------------- conv1d C_in=128, zero pad, act (1=relu,2=tanh), co-split across blockIdx.y
__global__ __launch_bounds__(256) void conv128_k(
    const float* __restrict__ src, int sbs,
    float* __restrict__ dst, int dbs,
    const float* __restrict__ wt, const float* __restrict__ bias, int act)
{
    int b = blockIdx.z, cb = blockIdx.y, tile = blockIdx.x, tid = threadIdx.x;
    int l0 = tile * 64;
    int tl4 = (tid & 15) * 4;
    int col = (tid >> 4) * 4;          // local co within 64-block
    __shared__ float xs[32 * 68];
    __shared__ float wsh[96 * 64];
    const float* sb = src + (size_t)b * sbs;
    float acc[4][4] = {};
    for (int chunk = 0; chunk < 4; ++chunk) {
        for (int idx = tid; idx < 32 * 66; idx += 256) {
            int ci = idx / 66, ll = idx - ci * 66;
            int gl = l0 - 1 + ll;
            xs[ci * 68 + ll] = (gl >= 0 && gl < 512) ? sb[(chunk * 32 + ci) * 512 + gl] : 0.f;
        }
        for (int idx = tid; idx < 96 * 16; idx += 256) {
            int row = idx >> 4, j = (idx & 15) * 4;
            *(float4*)(wsh + row * 64 + j) =
                *(const float4*)(wt + (size_t)(chunk * 96 + row) * 128 + cb * 64 + j);
        }
        __syncthreads();
        #pragma unroll 4
        for (int ci = 0; ci < 32; ++ci) {
            float x6[6];
            #pragma unroll
            for (int j = 0; j < 6; ++j) x6[j] = xs[ci * 68 + tl4 + j];
            #pragma unroll
            for (int k = 0; k < 3; ++k) {
                float w4[4];
                #pragma unroll
                for (int i = 0; i < 4; ++i) w4[i] = wsh[(ci * 3 + k) * 64 + col + i];
                #pragma unroll
                for (int i = 0; i < 4; ++i)
                    #pragma unroll
                    for (int j = 0; j < 4; ++j)
                        acc[i][j] = fmaf(w4[i], x6[k + j], acc[i][j]);
            }
        }
        __syncthreads();
    }
    #pragma unroll
    for (int i = 0; i < 4; ++i) {
        int co = cb * 64 + col + i;
        float bv = bias[co];
        float v[4];
        #pragma unroll
        for (int j = 0; j < 4; ++j) {
            float tv = acc[i][j] + bv;
            if (act == 1) tv = fmaxf(tv, 0.f);
            else if (act == 2) tv = tanhf(tv);
            v[j] = tv;
        }
        *(float4*)(dst + (size_t)b * dbs + (size_t)co * 512 + l0 + tl4) = *(float4*)v;
    }
}

// -------------------- hyT init: HY0 fp32 [b][co][l] (y layout) -> hyt bf16 [b][l][ci]
__global__ __launch_bounds__(256) void hyt_init_k(
    const float* __restrict__ hy0, unsigned short* __restrict__ hyt)
{
    int b = blockIdx.y, tile = blockIdx.x, tid = threadIdx.x;
    int l0 = tile * 64;
    __shared__ float xs[128 * 68];
    const float* sb = hy0 + (size_t)b * YB;
    for (int i = tid; i < 128 * 16; i += 256) {
        int co = i >> 4, lq = i & 15;
        float4 v = *(const float4*)(sb + (size_t)co * 512 + l0 + lq * 4);
        *(float4*)(xs + co * 68 + lq * 4) = v;
    }
    __syncthreads();
    for (int i = tid; i < 64 * 16; i += 256) {
        int l = i >> 4, c = i & 15;
        unsigned short pk[8];
        #pragma unroll
        for (int q = 0; q < 8; ++q) pk[q] = f2bf(xs[(c * 8 + q) * 68 + l]);
        *(uint4*)(hyt + ((size_t)b * 512 + l0 + l) * 128 + c * 8) = *(uint4*)pk;
    }
}

// -------------------- recurrent step: MFMA circular conv + fused update -----
// D[l][co] = sum_kappa hyT[l+k-1][ci] * w2[co][kappa]; then pointwise update.
__global__ __launch_bounds__(256) void recur_k(
    const unsigned short* __restrict__ hyt_in,
    unsigned short* __restrict__ hyt_out,
    const float* __restrict__ y_prev,   // hy_{t-1} fp32, y-slab base (b-stride YB)
    float* __restrict__ y_out,          // hy_t slab base
    const float* __restrict__ omega, const float* __restrict__ alpha,
    float* __restrict__ hz,
    const unsigned short* __restrict__ w2,
    float* __restrict__ part, int t)
{
    int b = blockIdx.y, tile = blockIdx.x, tid = threadIdx.x;
    int l0 = tile * 64;
    int lane = tid & 63;
    int w = tid >> 6;          // wave 0..3
    int wl = w >> 1;           // l-half (32 l)
    int wc = w & 1;            // co-half (64 co)
    int lr = lane & 15, kg = lane >> 4;

    __shared__ uint4 hyS[66 * 16];            // stage-in: 66 rows x 16 chunks, chunk-swizzled
    __shared__ float part_s[2][4][2][16];

    // ---- stage-in hy bf16 rows (circular halo), swizzle chunks: c' = c ^ (r&7)
    const unsigned short* hb = hyt_in + (size_t)b * 65536;
    for (int i = tid; i < 66 * 16; i += 256) {
        int r = i >> 4, c = i & 15;
        int gl = (l0 - 1 + r + 512) & 511;
        hyS[r * 16 + (c ^ (r & 7))] = *(const uint4*)(hb + (size_t)gl * 128 + c * 8);
    }
    __syncthreads();

    f32x4 acc[2][4];
    #pragma unroll
    for (int i = 0; i < 2; ++i)
        #pragma unroll
        for (int j = 0; j < 4; ++j) acc[i][j] = (f32x4){0.f, 0.f, 0.f, 0.f};

    #pragma unroll
    for (int s = 0; s < 12; ++s) {
        int k = s >> 2;
        int cbase = (s & 3) * 4 + kg;                     // ci chunk index
        int rl = wl * 32 + lr + k;                        // LDS row for A frag 0
        int r2 = rl + 16;
        bf16x8 a0 = __builtin_bit_cast(bf16x8, hyS[rl * 16 + (cbase ^ (rl & 7))]);
        bf16x8 a1 = __builtin_bit_cast(bf16x8, hyS[r2 * 16 + (cbase ^ (r2 & 7))]);
        #pragma unroll
        for (int cf = 0; cf < 4; ++cf) {
            int co = wc * 64 + cf * 16 + lr;
            bf16x8 bf = *(const bf16x8*)(w2 + (size_t)co * 384 + s * 32 + kg * 8);
            acc[0][cf] = __builtin_amdgcn_mfma_f32_16x16x32_bf16(a0, bf, acc[0][cf], 0, 0, 0);
            acc[1][cf] = __builtin_amdgcn_mfma_f32_16x16x32_bf16(a1, bf, acc[1][cf], 0, 0, 0);
        }
    }
    __syncthreads();   // all LDS reads done block-wide; safe to overwrite

    unsigned short* hyS16 = (unsigned short*)hyS;   // stage-out rows 0..63 linear [l][ci]
    float lsum[4] = {0.f, 0.f, 0.f, 0.f};

    #pragma unroll
    for (int af = 0; af < 2; ++af) {
        int ll = wl * 32 + af * 16 + kg * 4;      // l_local base (4 consecutive)
        int lg = l0 + ll;
        #pragma unroll
        for (int cf = 0; cf < 4; ++cf) {
            int co = wc * 64 + cf * 16 + lr;
            size_t off = ((size_t)b * 128 + co) * 512 + lg;
            float4 om = *(const float4*)(omega + off);
            float4 al = *(const float4*)(alpha + off);
            float4 hp = *(const float4*)(y_prev + (size_t)b * YB + (size_t)co * 512 + lg);
            float4 hzv;
            if (t == 0) hzv = make_float4(0.f, 0.f, 0.f, 0.f);
            else        hzv = *(const float4*)(hz + off);
            float hyn[4], hzn[4];
            const float* accp = (const float*)&acc[af][cf];
            const float* omp = (const float*)&om;
            const float* alp = (const float*)&al;
            const float* hpp = (const float*)&hp;
            const float* hzp = (const float*)&hzv;
            #pragma unroll
            for (int r = 0; r < 4; ++r) {
                float spring = tanh_fast(accp[r]);
                float zn = hzp[r] + DTc * (spring - omp[r] * hpp[r] - alp[r] * hzp[r]);
                float hn = hpp[r] + DTc * zn;
                hzn[r] = zn; hyn[r] = hn;
                lsum[cf] += hn;
            }
            *(float4*)(hz + off) = *(float4*)hzn;
            *(float4*)(y_out + (size_t)b * YB + (size_t)co * 512 + lg) = *(float4*)hyn;
            #pragma unroll
            for (int r = 0; r < 4; ++r)
                hyS16[(ll + r) * 128 + co] = f2bf(hyn[r]);
        }
    }

    // per-co partial sums over l (for ybar): reduce across kg groups, then wl via LDS
    #pragma unroll
    for (int cf = 0; cf < 4; ++cf) {
        float s = lsum[cf];
        s += __shfl_xor(s, 16);
        s += __shfl_xor(s, 32);
        if (kg == 0) part_s[wc][cf][wl][lr] = s;
    }
    __syncthreads();

    // copy out new hyT rows (coalesced)
    for (int i = tid; i < 64 * 16; i += 256) {
        int r = i >> 4, c = i & 15;
        *(uint4*)(hyt_out + ((size_t)b * 512 + l0 + r) * 128 + c * 8) = hyS[r * 16 + c];
    }
    if (tid < 128) {
        int co = tid;  // wc=tid>>6, cf=(tid>>4)&3, lr=tid&15  -> co == tid
        float v = part_s[tid >> 6][(tid >> 4) & 3][0][tid & 15]
                + part_s[tid >> 6][(tid >> 4) & 3][1][tid & 15];
        part[(((size_t)b * 50 + t) * 128 + co) * 8 + tile] = v;
    }
}

// -------------------- readout ----------------------------------------------
__global__ __launch_bounds__(256) void readout_k(
    const float* __restrict__ part, const float* __restrict__ fct,
    const float* __restrict__ rw1, const float* __restrict__ rb1,
    const float* __restrict__ rw2, const float* __restrict__ rb2,
    const float* __restrict__ rw3, const float* __restrict__ rb3,
    float* __restrict__ out)
{
    int b = blockIdx.x, tid = threadIdx.x;
    __shared__ float ybar[50 * 128];
    __shared__ float feat[26 * 128];
    __shared__ float h1[64];
    __shared__ float h2[32];
    for (int idx = tid; idx < 50 * 128; idx += 256) {
        const float* p = part + ((size_t)b * 6400 + idx) * 8;
        float s = 0.f;
        #pragma unroll
        for (int q = 0; q < 8; ++q) s += p[q];
        ybar[idx] = s * (1.f / 512.f);
    }
    __syncthreads();
    for (int idx = tid; idx < 26 * 128; idx += 256) {
        int k = idx >> 7, c = idx & 127;
        float s = 0.f;
        for (int t = 0; t < 50; ++t) s += fct[k * 50 + t] * ybar[t * 128 + c];
        feat[idx] = s;
    }
    __syncthreads();
    {
        int j = tid >> 2, q = tid & 3;
        float s = 0.f;
        const float* r = rw1 + (size_t)j * 3328 + q * 832;
        const float* f = feat + q * 832;
        for (int i = 0; i < 832; ++i) s += f[i] * r[i];
        s += __shfl_xor(s, 1);
        s += __shfl_xor(s, 2);
        if (q == 0) h1[j] = fmaxf(s + rb1[j], 0.f);
    }
    __syncthreads();
    if (tid < 32) {
        float s = 0.f;
        for (int i = 0; i < 64; ++i) s += h1[i] * rw2[tid * 64 + i];
        h2[tid] = fmaxf(s + rb2[tid], 0.f);
    }
    __syncthreads();
    if (tid == 0) {
        float s = 0.f;
        for (int i = 0; i < 32; ++i) s += h2[i] * rw3[i];
        out[b] = s + rb3[0];
    }
}

// -------------------- launch ------------------------------------------------
extern "C" void kernel_launch(void* const* d_in, const int* in_sizes, int n_in,
                              void* d_out, int out_size, void* d_ws, size_t ws_size,
                              hipStream_t stream)
{
    const float* x   = (const float*)d_in[0];
    const float* ow1 = (const float*)d_in[1];  const float* ob1 = (const float*)d_in[2];
    const float* ow2 = (const float*)d_in[3];  const float* ob2 = (const float*)d_in[4];
    const float* ow3 = (const float*)d_in[5];  const float* ob3 = (const float*)d_in[6];
    const float* aw1 = (const float*)d_in[7];  const float* ab1 = (const float*)d_in[8];
    const float* aw2 = (const float*)d_in[9];  const float* ab2 = (const float*)d_in[10];
    const float* aw3 = (const float*)d_in[11]; const float* ab3 = (const float*)d_in[12];
    const float* hw1 = (const float*)d_in[13]; const float* hb1 = (const float*)d_in[14];
    const float* hw2 = (const float*)d_in[15]; const float* hb2 = (const float*)d_in[16];
    const float* hw3 = (const float*)d_in[17]; const float* hb3 = (const float*)d_in[18];
    const float* hw4 = (const float*)d_in[19]; const float* hb4 = (const float*)d_in[20];
    const float* wy  = (const float*)d_in[21];
    const float* fct = (const float*)d_in[22];
    const float* rw1 = (const float*)d_in[23]; const float* rb1 = (const float*)d_in[24];
    const float* rw2 = (const float*)d_in[25]; const float* rb2 = (const float*)d_in[26];
    const float* rw3 = (const float*)d_in[27]; const float* rb3 = (const float*)d_in[28];

    float* out  = (float*)d_out;
    float* yout = out + 32;                       // y_seq region
    float* ws   = (float*)d_ws;

    // ws layout (float offsets)
    float* OMEGA = ws;                            // 2097152
    float* ALPHA = ws + 2097152;                  // 2097152
    float* HZ    = ws + 4194304;                  // 2097152
    float* WT    = ws + 6291456;                  // 353280 (encoder transposes)
    float* PART  = ws + 6644736;                  // 1638400
    unsigned short* HYT = (unsigned short*)(ws + 8283136);  // 2 x 2097152 bf16
    unsigned short* W2  = HYT + 4194304;                    // 49152 bf16
    // total ~41.6 MB

    // scratch in the y_seq region (overwritten by steps 48/49 after last use)
    float* TMP1 = yout + 49 * YT;                 // b-stride YB
    float* HY0  = yout + 48 * YT;                 // b-stride YB

    float* OW1T = WT + 0;      float* AW1T = WT + 3072;   float* HW1T = WT + 6144;
    float* OW2T = WT + 9216;   float* OW3T = WT + 58368;
    float* AW2T = WT + 107520; float* AW3T = WT + 156672;
    float* HW2T = WT + 205824; float* HW3T = WT + 254976; float* HW4T = WT + 304128;

    // weight preps
    wtrans_k<<<12, 256, 0, stream>>>(ow1, OW1T, 8);
    wtrans_k<<<12, 256, 0, stream>>>(aw1, AW1T, 8);
    wtrans_k<<<12, 256, 0, stream>>>(hw1, HW1T, 8);
    wtrans_k<<<192, 256, 0, stream>>>(ow2, OW2T, 128);
    wtrans_k<<<192, 256, 0, stream>>>(ow3, OW3T, 128);
    wtrans_k<<<192, 256, 0, stream>>>(aw2, AW2T, 128);
    wtrans_k<<<192, 256, 0, stream>>>(aw3, AW3T, 128);
    wtrans_k<<<192, 256, 0, stream>>>(hw2, HW2T, 128);
    wtrans_k<<<192, 256, 0, stream>>>(hw3, HW3T, 128);
    wtrans_k<<<192, 256, 0, stream>>>(hw4, HW4T, 128);
    wprep_k <<<192, 256, 0, stream>>>(wy, W2);

    dim3 g8(8, 32);
    dim3 gc(8, 2, 32);

    // omega encoder
    conv8_k  <<<g8, 256, 0, stream>>>(x, 8 * 512, TMP1, YB, OW1T, ob1);
    conv128_k<<<gc, 256, 0, stream>>>(TMP1, YB, HZ, 128 * 512, OW2T, ob2, 1);
    conv128_k<<<gc, 256, 0, stream>>>(HZ, 128 * 512, OMEGA, 128 * 512, OW3T, ob3, 1);
    // alpha encoder
    conv8_k  <<<g8, 256, 0, stream>>>(x, 8 * 512, TMP1, YB, AW1T, ab1);
    conv128_k<<<gc, 256, 0, stream>>>(TMP1, YB, HZ, 128 * 512, AW2T, ab2, 1);
    conv128_k<<<gc, 256, 0, stream>>>(HZ, 128 * 512, ALPHA, 128 * 512, AW3T, ab3, 1);
    // hy encoder
    conv8_k  <<<g8, 256, 0, stream>>>(x, 8 * 512, TMP1, YB, HW1T, hb1);
    conv128_k<<<gc, 256, 0, stream>>>(TMP1, YB, HZ, 128 * 512, HW2T, hb2, 1);
    conv128_k<<<gc, 256, 0, stream>>>(HZ, 128 * 512, TMP1, YB, HW3T, hb3, 1);
    conv128_k<<<gc, 256, 0, stream>>>(TMP1, YB, HY0, YB, HW4T, hb4, 2);

    // initial bf16 transposed hy
    hyt_init_k<<<g8, 256, 0, stream>>>(HY0, HYT);

    // recurrence
    for (int t = 0; t < Tsteps; ++t) {
        const unsigned short* hin = HYT + (size_t)(t & 1) * 2097152;
        unsigned short* hout      = HYT + (size_t)((t + 1) & 1) * 2097152;
        const float* yprev = (t == 0) ? HY0 : (yout + (size_t)(t - 1) * YT);
        recur_k<<<g8, 256, 0, stream>>>(hin, hout, yprev, yout + (size_t)t * YT,
                                        OMEGA, ALPHA, HZ, W2, PART, t);
    }

    // readout
    readout_k<<<32, 256, 0, stream>>>(PART, fct, rw1, rb1, rw2, rb2, rw3, rb3, out);
}

// Round 3
// 1205.928 us; speedup vs baseline: 2.6072x; 1.2424x over previous
//
#include <hip/hip_runtime.h>
#include <math.h>

#define YB (50*128*512)   // y_seq batch stride (floats)
#define YT (128*512)      // y_seq time stride
#define DTc 0.5f
#define NBLK 256

typedef __attribute__((ext_vector_type(8))) short bf16x8;
typedef __attribute__((ext_vector_type(4))) float f32x4;

__device__ __forceinline__ unsigned short f2bf(float f) {
    unsigned int u = __builtin_bit_cast(unsigned int, f);
    u += 0x7fffu + ((u >> 16) & 1u);          // RNE
    return (unsigned short)(u >> 16);
}

__device__ __forceinline__ float tanh_fast(float x) {
    float ax = fabsf(x);
    float e  = __expf(-2.f * ax);
    float r  = (1.f - e) * __builtin_amdgcn_rcpf(1.f + e);
    return __builtin_copysignf(r, x);
}

// ==================== fused weight prep ====================
// WT layout: OW1T@0 AW1T@3072 HW1T@6144 then 7x 49152: ow2,ow3,aw2,aw3,hw2,hw3,hw4
// W2: bf16 [co][kappa=384], kappa=s*32+u, k=s>>2, ci=(s&3)*32+u
struct WSrc { const float* p[11]; };  // ow1,aw1,hw1, ow2,ow3,aw2,aw3,hw2,hw3,hw4, wy
__global__ void wprep_all_k(WSrc s, float* __restrict__ wt, unsigned short* __restrict__ w2) {
    int idx = blockIdx.x * 256 + threadIdx.x;
    if (idx < 9216) {
        int wsel = idx / 3072, r = idx % 3072;
        int row = r >> 7, co = r & 127;
        int ci = row / 3, k = row - ci * 3;
        wt[idx] = s.p[wsel][(co * 8 + ci) * 3 + k];
    } else if (idx < 353280) {
        int r = idx - 9216;
        int wsel = 3 + r / 49152, q = r % 49152;
        int row = q >> 7, co = q & 127;
        int ci = row / 3, k = row - ci * 3;
        wt[idx] = s.p[wsel][(co * 128 + ci) * 3 + k];
    } else if (idx < 402432) {
        int q = idx - 353280;
        int co = q / 384, kap = q - co * 384;
        int k = kap >> 7;
        int ci = ((kap >> 5) & 3) * 32 + (kap & 31);
        w2[q] = f2bf(s.p[10][(co * 128 + ci) * 3 + k]);
    }
}

// ==================== encoder convs (fp32, job-batched) ====================
struct Job { const float* src; float* dst; const float* wt; const float* bias; int sbs, dbs, act; };
struct Jobs3 { Job j[3]; };

__global__ __launch_bounds__(256) void conv8x3_k(Jobs3 js) {
    int jb = blockIdx.y % 3;     // grid y = 3
    Job jo = js.j[jb];
    int b = blockIdx.z, tile = blockIdx.x, tid = threadIdx.x;
    int l0 = tile * 64;
    int tl4 = (tid & 15) * 4;
    int co0 = (tid >> 4) * 8;
    __shared__ float xs[8 * 68];
    __shared__ float wsh[24 * 128];
    const float* sb = jo.src + (size_t)b * jo.sbs;
    for (int idx = tid; idx < 8 * 66; idx += 256) {
        int ci = idx / 66, ll = idx - ci * 66;
        int gl = l0 - 1 + ll;
        xs[ci * 68 + ll] = (gl >= 0 && gl < 512) ? sb[ci * 512 + gl] : 0.f;
    }
    for (int idx = tid; idx < 24 * 128; idx += 256) wsh[idx] = jo.wt[idx];
    __syncthreads();
    float acc[8][4] = {};
    #pragma unroll
    for (int ci = 0; ci < 8; ++ci) {
        float x6[6];
        #pragma unroll
        for (int j = 0; j < 6; ++j) x6[j] = xs[ci * 68 + tl4 + j];
        #pragma unroll
        for (int k = 0; k < 3; ++k) {
            float w8[8];
            #pragma unroll
            for (int i = 0; i < 8; ++i) w8[i] = wsh[(ci * 3 + k) * 128 + co0 + i];
            #pragma unroll
            for (int i = 0; i < 8; ++i)
                #pragma unroll
                for (int j = 0; j < 4; ++j)
                    acc[i][j] = fmaf(w8[i], x6[k + j], acc[i][j]);
        }
    }
    #pragma unroll
    for (int i = 0; i < 8; ++i) {
        int co = co0 + i;
        float bv = jo.bias[co];
        float4 o;
        o.x = fmaxf(acc[i][0] + bv, 0.f);
        o.y = fmaxf(acc[i][1] + bv, 0.f);
        o.z = fmaxf(acc[i][2] + bv, 0.f);
        o.w = fmaxf(acc[i][3] + bv, 0.f);
        *(float4*)(jo.dst + (size_t)b * jo.dbs + (size_t)co * 512 + l0 + tl4) = o;
    }
}

__global__ __launch_bounds__(256) void conv128x3_k(Jobs3 js) {
    int jb = blockIdx.y >> 1, cb = blockIdx.y & 1;
    Job jo = js.j[jb];
    int b = blockIdx.z, tile = blockIdx.x, tid = threadIdx.x;
    int l0 = tile * 64;
    int tl4 = (tid & 15) * 4;
    int col = (tid >> 4) * 4;
    __shared__ float xs[32 * 68];
    __shared__ float wsh[96 * 64];
    const float* sb = jo.src + (size_t)b * jo.sbs;
    float acc[4][4] = {};
    for (int chunk = 0; chunk < 4; ++chunk) {
        for (int idx = tid; idx < 32 * 66; idx += 256) {
            int ci = idx / 66, ll = idx - ci * 66;
            int gl = l0 - 1 + ll;
            xs[ci * 68 + ll] = (gl >= 0 && gl < 512) ? sb[(chunk * 32 + ci) * 512 + gl] : 0.f;
        }
        for (int idx = tid; idx < 96 * 16; idx += 256) {
            int row = idx >> 4, j = (idx & 15) * 4;
            *(float4*)(wsh + row * 64 + j) =
                *(const float4*)(jo.wt + (size_t)(chunk * 96 + row) * 128 + cb * 64 + j);
        }
        __syncthreads();
        #pragma unroll 4
        for (int ci = 0; ci < 32; ++ci) {
            float x6[6];
            #pragma unroll
            for (int j = 0; j < 6; ++j) x6[j] = xs[ci * 68 + tl4 + j];
            #pragma unroll
            for (int k = 0; k < 3; ++k) {
                float w4[4];
                #pragma unroll
                for (int i = 0; i < 4; ++i) w4[i] = wsh[(ci * 3 + k) * 64 + col + i];
                #pragma unroll
                for (int i = 0; i < 4; ++i)
                    #pragma unroll
                    for (int j = 0; j < 4; ++j)
                        acc[i][j] = fmaf(w4[i], x6[k + j], acc[i][j]);
            }
        }
        __syncthreads();
    }
    #pragma unroll
    for (int i = 0; i < 4; ++i) {
        int co = cb * 64 + col + i;
        float bv = jo.bias[co];
        float v[4];
        #pragma unroll
        for (int j = 0; j < 4; ++j) {
            float tv = acc[i][j] + bv;
            if (jo.act == 1) tv = fmaxf(tv, 0.f);
            else if (jo.act == 2) tv = tanhf(tv);
            v[j] = tv;
        }
        *(float4*)(jo.dst + (size_t)b * jo.dbs + (size_t)co * 512 + l0 + tl4) = *(float4*)v;
    }
}

// ==================== grid barrier ====================
__global__ void zero_bar_k(unsigned* bar) { if (threadIdx.x < 2) bar[threadIdx.x] = 0u; }

__device__ __forceinline__ void grid_barrier(unsigned* bar) {
    // bar[0]=cnt, bar[1]=gen. Generation-relative: safe across graph replays.
    unsigned g = __hip_atomic_load(bar + 1, __ATOMIC_ACQUIRE, __HIP_MEMORY_SCOPE_AGENT);
    unsigned a = __hip_atomic_fetch_add(bar, 1u, __ATOMIC_ACQ_REL, __HIP_MEMORY_SCOPE_AGENT);
    if (a == NBLK - 1) {
        __hip_atomic_store(bar, 0u, __ATOMIC_RELAXED, __HIP_MEMORY_SCOPE_AGENT);
        __hip_atomic_fetch_add(bar + 1, 1u, __ATOMIC_ACQ_REL, __HIP_MEMORY_SCOPE_AGENT);
    } else {
        while (__hip_atomic_load(bar + 1, __ATOMIC_ACQUIRE, __HIP_MEMORY_SCOPE_AGENT) == g)
            __builtin_amdgcn_s_sleep(8);
    }
}

// ==================== persistent recurrence ====================
// Block (tile,b): W=80 state rows (l = l0-8 .. l0+71) x 128 co.
// State in regs (MFMA D-layout): lane (wid=ct, lr, kg) holds co=ct*16+lr,
// rows 16*lt + kg*4 + j (lt=0..4, j=0..3). hyS bf16 [82 rows][128 ci] swizzled.
// Chunk = 8 steps; halo refresh through y slab + parity HZE + grid barrier.
__global__ __launch_bounds__(512, 2) void recur_fused_k(
    const float* __restrict__ hy0,     // [b][co][l], b-stride YB
    const float* __restrict__ omega,   // [b][co][l], b-stride 65536
    const float* __restrict__ alpha,
    const unsigned short* __restrict__ w2,
    float* __restrict__ yout,          // slab 0 base
    float* __restrict__ hze,           // [2][32][8][128][16] f32
    float* __restrict__ part,          // [32][50][128][8]
    unsigned* __restrict__ bar)
{
    int tile = blockIdx.x, b = blockIdx.y;
    int tid = threadIdx.x, lane = tid & 63, wid = tid >> 6;
    int lr = lane & 15, kg = lane >> 4;
    int co = wid * 16 + lr;
    int l0 = tile * 64;

    __shared__ uint4 hyS4[82 * 16];            // [row][chunk ^ (row&7)]
    __shared__ float temp[128 * 92];           // staging, [co][92]
    unsigned short* hyS16 = (unsigned short*)hyS4;

    // ---- B weights (once)
    bf16x8 Bw[12];
    {
        const bf16x8* wp = (const bf16x8*)(w2 + (size_t)co * 384);
        #pragma unroll
        for (int s = 0; s < 12; ++s) Bw[s] = wp[s * 4 + kg];
    }

    // ---- stage+load initial state
    f32x4 hyR[5], hzR[5], omR[5], alR[5];

    // hy
    for (int i = tid; i < 128 * 22; i += 512) {
        int c = i / 22, p4 = (i - c * 22) * 4;
        int l = (l0 - 12 + p4) & 511;
        *(f32x4*)(temp + c * 92 + p4) = *(const f32x4*)(hy0 + (size_t)b * YB + (size_t)c * 512 + l);
    }
    __syncthreads();
    #pragma unroll
    for (int lt = 0; lt < 5; ++lt)
        hyR[lt] = *(const f32x4*)(temp + co * 92 + 16 * lt + kg * 4 + 4);
    for (int i = tid; i < 82 * 16; i += 512) {
        int h = i >> 4, c8 = i & 15;
        unsigned short pk[8];
        #pragma unroll
        for (int q = 0; q < 8; ++q) pk[q] = f2bf(temp[(c8 * 8 + q) * 92 + (h + 3)]);
        hyS4[h * 16 + (c8 ^ (h & 7))] = *(uint4*)pk;
    }
    __syncthreads();
    // omega
    for (int i = tid; i < 128 * 22; i += 512) {
        int c = i / 22, p4 = (i - c * 22) * 4;
        int l = (l0 - 12 + p4) & 511;
        *(f32x4*)(temp + c * 92 + p4) = *(const f32x4*)(omega + (size_t)b * 65536 + (size_t)c * 512 + l);
    }
    __syncthreads();
    #pragma unroll
    for (int lt = 0; lt < 5; ++lt)
        omR[lt] = *(const f32x4*)(temp + co * 92 + 16 * lt + kg * 4 + 4);
    __syncthreads();
    // alpha
    for (int i = tid; i < 128 * 22; i += 512) {
        int c = i / 22, p4 = (i - c * 22) * 4;
        int l = (l0 - 12 + p4) & 511;
        *(f32x4*)(temp + c * 92 + p4) = *(const f32x4*)(alpha + (size_t)b * 65536 + (size_t)c * 512 + l);
    }
    __syncthreads();
    #pragma unroll
    for (int lt = 0; lt < 5; ++lt)
        alR[lt] = *(const f32x4*)(temp + co * 92 + 16 * lt + kg * 4 + 4);
    #pragma unroll
    for (int lt = 0; lt < 5; ++lt) hzR[lt] = (f32x4){0.f, 0.f, 0.f, 0.f};
    __syncthreads();

    // ---- main loop
    for (int t = 0; t < 50; ++t) {
        // MFMA: conv over hyS
        f32x4 acc[5];
        #pragma unroll
        for (int lt = 0; lt < 5; ++lt) acc[lt] = (f32x4){0.f, 0.f, 0.f, 0.f};
        #pragma unroll
        for (int s = 0; s < 12; ++s) {
            int k = s >> 2;
            int arow = lr + k;
            int aidx = arow * 16 + ((arow & 7) ^ ((s & 3) * 4 + kg));
            bf16x8 Bf = Bw[s];
            #pragma unroll
            for (int lt = 0; lt < 5; ++lt) {
                bf16x8 a = __builtin_bit_cast(bf16x8, hyS4[aidx + lt * 256]);
                acc[lt] = __builtin_amdgcn_mfma_f32_16x16x32_bf16(a, Bf, acc[lt], 0, 0, 0);
            }
        }
        __syncthreads();   // all hyS reads complete

        // pointwise update + y write + hyS rewrite
        float lsum = 0.f;
        float* yslab = yout + (size_t)b * YB + (size_t)t * YT + (size_t)co * 512;
        #pragma unroll
        for (int lt = 0; lt < 5; ++lt) {
            #pragma unroll
            for (int j = 0; j < 4; ++j) {
                float spring = tanh_fast(acc[lt][j]);
                float zn = hzR[lt][j] + DTc * (spring - omR[lt][j] * hyR[lt][j] - alR[lt][j] * hzR[lt][j]);
                float hn = hyR[lt][j] + DTc * zn;
                hzR[lt][j] = zn;
                hyR[lt][j] = hn;
            }
            bool valid = (lt > 0 || kg >= 2) && (lt < 4 || kg < 2);
            if (valid) {
                int r0 = lt * 16 + kg * 4;
                *(f32x4*)(yslab + (l0 - 8 + r0)) = hyR[lt];
                lsum += hyR[lt][0] + hyR[lt][1] + hyR[lt][2] + hyR[lt][3];
            }
            if (t < 49) {
                #pragma unroll
                for (int j = 0; j < 4; ++j) {
                    int rr = lt * 16 + kg * 4 + j + 1;   // hyS row
                    int sidx = rr * 128 + (((co >> 3) ^ (rr & 7)) << 3) + (co & 7);
                    hyS16[sidx] = f2bf(hyR[lt][j]);
                }
            }
        }
        lsum += __shfl_xor(lsum, 16);
        lsum += __shfl_xor(lsum, 32);
        if (kg == 0) part[(((size_t)b * 50 + t) * 128 + co) * 8 + tile] = lsum;

        if ((t & 7) == 7 && t < 49) {
            // ---- chunk boundary: halo exchange
            int par = (t >> 3) & 1;
            float* hb = hze + ((((size_t)par * 32 + b) * 8 + tile) * 128 + co) * 16;
            if (kg >= 2) *(f32x4*)(hb + (kg - 2) * 4) = hzR[0];  // center rows 8..15 -> e 0..7
            else         *(f32x4*)(hb + 8 + kg * 4)  = hzR[4];  // center rows 64..71 -> e 8..15
            __threadfence();
            __syncthreads();
            if (tid == 0) grid_barrier(bar);
            __syncthreads();
            __threadfence();
            // refresh halo regs
            const float* ycur = yout + (size_t)b * YB + (size_t)t * YT;
            if (kg < 2) {        // state rows 0..7 (lt0)
                int l = (l0 - 8 + kg * 4) & 511;
                hyR[0] = *(const f32x4*)(ycur + (size_t)co * 512 + l);
                const float* hbl = hze + ((((size_t)par * 32 + b) * 8 + ((tile + 7) & 7)) * 128 + co) * 16;
                hzR[0] = *(const f32x4*)(hbl + 8 + kg * 4);
            } else {             // state rows 72..79 (lt4)
                int l = (l0 + 64 + (kg - 2) * 4) & 511;
                hyR[4] = *(const f32x4*)(ycur + (size_t)co * 512 + l);
                const float* hbr = hze + ((((size_t)par * 32 + b) * 8 + ((tile + 1) & 7)) * 128 + co) * 16;
                hzR[4] = *(const f32x4*)(hbr + (kg - 2) * 4);
            }
            // refresh hyS halo rows 0..8, 73..81
            for (int i = tid; i < 18 * 128; i += 512) {
                int hr = i >> 7, c2 = i & 127;
                int h = (hr < 9) ? hr : (64 + hr);
                int l = (l0 - 9 + h) & 511;
                float v = ycur[(size_t)c2 * 512 + l];
                int sidx = h * 128 + (((c2 >> 3) ^ (h & 7)) << 3) + (c2 & 7);
                hyS16[sidx] = f2bf(v);
            }
            __syncthreads();
        } else if (t < 49) {
            __syncthreads();   // hyS writes visible for next step
        }
    }
}

// ==================== readout ====================
__global__ __launch_bounds__(256) void readout_k(
    const float* __restrict__ part, const float* __restrict__ fct,
    const float* __restrict__ rw1, const float* __restrict__ rb1,
    const float* __restrict__ rw2, const float* __restrict__ rb2,
    const float* __restrict__ rw3, const float* __restrict__ rb3,
    float* __restrict__ out)
{
    int b = blockIdx.x, tid = threadIdx.x;
    __shared__ float ybar[50 * 128];
    __shared__ float feat[26 * 128];
    __shared__ float h1[64];
    __shared__ float h2[32];
    for (int idx = tid; idx < 50 * 128; idx += 256) {
        const float* p = part + ((size_t)b * 6400 + idx) * 8;
        float s = 0.f;
        #pragma unroll
        for (int q = 0; q < 8; ++q) s += p[q];
        ybar[idx] = s * (1.f / 512.f);
    }
    __syncthreads();
    for (int idx = tid; idx < 26 * 128; idx += 256) {
        int k = idx >> 7, c = idx & 127;
        float s = 0.f;
        for (int t = 0; t < 50; ++t) s += fct[k * 50 + t] * ybar[t * 128 + c];
        feat[idx] = s;
    }
    __syncthreads();
    {
        int j = tid >> 2, q = tid & 3;
        float s = 0.f;
        const float* r = rw1 + (size_t)j * 3328 + q * 832;
        const float* f = feat + q * 832;
        for (int i = 0; i < 832; ++i) s += f[i] * r[i];
        s += __shfl_xor(s, 1);
        s += __shfl_xor(s, 2);
        if (q == 0) h1[j] = fmaxf(s + rb1[j], 0.f);
    }
    __syncthreads();
    if (tid < 32) {
        float s = 0.f;
        for (int i = 0; i < 64; ++i) s += h1[i] * rw2[tid * 64 + i];
        h2[tid] = fmaxf(s + rb2[tid], 0.f);
    }
    __syncthreads();
    if (tid == 0) {
        float s = 0.f;
        for (int i = 0; i < 32; ++i) s += h2[i] * rw3[i];
        out[b] = s + rb3[0];
    }
}

// ==================== launch ====================
extern "C" void kernel_launch(void* const* d_in, const int* in_sizes, int n_in,
                              void* d_out, int out_size, void* d_ws, size_t ws_size,
                              hipStream_t stream)
{
    const float* x   = (const float*)d_in[0];
    const float* ow1 = (const float*)d_in[1];  const float* ob1 = (const float*)d_in[2];
    const float* ow2 = (const float*)d_in[3];  const float* ob2 = (const float*)d_in[4];
    const float* ow3 = (const float*)d_in[5];  const float* ob3 = (const float*)d_in[6];
    const float* aw1 = (const float*)d_in[7];  const float* ab1 = (const float*)d_in[8];
    const float* aw2 = (const float*)d_in[9];  const float* ab2 = (const float*)d_in[10];
    const float* aw3 = (const float*)d_in[11]; const float* ab3 = (const float*)d_in[12];
    const float* hw1 = (const float*)d_in[13]; const float* hb1 = (const float*)d_in[14];
    const float* hw2 = (const float*)d_in[15]; const float* hb2 = (const float*)d_in[16];
    const float* hw3 = (const float*)d_in[17]; const float* hb3 = (const float*)d_in[18];
    const float* hw4 = (const float*)d_in[19]; const float* hb4 = (const float*)d_in[20];
    const float* wy  = (const float*)d_in[21];
    const float* fct = (const float*)d_in[22];
    const float* rw1 = (const float*)d_in[23]; const float* rb1 = (const float*)d_in[24];
    const float* rw2 = (const float*)d_in[25]; const float* rb2 = (const float*)d_in[26];
    const float* rw3 = (const float*)d_in[27]; const float* rb3 = (const float*)d_in[28];

    float* out  = (float*)d_out;
    float* yout = out + 32;                       // y_seq region
    float* ws   = (float*)d_ws;

    // ws layout (float offsets)
    float* OMEGA = ws;                            // 2097152
    float* ALPHA = ws + 2097152;                  // 2097152
    float* WT    = ws + 4194304;                  // 353280
    float* PART  = ws + 4547584;                  // 1638400
    float* HZE   = ws + 6185984;                  // 1048576
    unsigned short* W2 = (unsigned short*)(ws + 7234560);  // 49152 u16
    unsigned* BAR = (unsigned*)(ws + 7259136);    // 2 u32
    // total ~29 MB

    // encoder scratch slabs in y region (overwritten at step t >= slab index,
    // long after last encoder use — all encoder work precedes the recurrence)
    float* To1 = yout + 44 * YT;
    float* Ta1 = yout + 45 * YT;
    float* Th1 = yout + 46 * YT;
    float* To2 = yout + 47 * YT;
    float* Ta2 = yout + 43 * YT;
    float* Th2 = yout + 49 * YT;
    float* Th3 = yout + 42 * YT;
    float* HY0 = yout + 48 * YT;

    float* OW1T = WT + 0;      float* AW1T = WT + 3072;   float* HW1T = WT + 6144;
    float* OW2T = WT + 9216;   float* OW3T = WT + 58368;
    float* AW2T = WT + 107520; float* AW3T = WT + 156672;
    float* HW2T = WT + 205824; float* HW3T = WT + 254976; float* HW4T = WT + 304128;

    // ---- weight prep (1 launch)
    WSrc wsrc;
    wsrc.p[0] = ow1; wsrc.p[1] = aw1; wsrc.p[2] = hw1;
    wsrc.p[3] = ow2; wsrc.p[4] = ow3; wsrc.p[5] = aw2; wsrc.p[6] = aw3;
    wsrc.p[7] = hw2; wsrc.p[8] = hw3; wsrc.p[9] = hw4; wsrc.p[10] = wy;
    wprep_all_k<<<1572, 256, 0, stream>>>(wsrc, WT, W2);

    // ---- encoders (4 launches)
    Jobs3 d1 = {{ {x, To1, OW1T, ob1, 4096, YB, 1},
                  {x, Ta1, AW1T, ab1, 4096, YB, 1},
                  {x, Th1, HW1T, hb1, 4096, YB, 1} }};
    conv8x3_k<<<dim3(8, 3, 32), 256, 0, stream>>>(d1);

    Jobs3 d2 = {{ {To1, To2, OW2T, ob2, YB, YB, 1},
                  {Ta1, Ta2, AW2T, ab2, YB, YB, 1},
                  {Th1, Th2, HW2T, hb2, YB, YB, 1} }};
    conv128x3_k<<<dim3(8, 6, 32), 256, 0, stream>>>(d2);

    Jobs3 d3 = {{ {To2, OMEGA, OW3T, ob3, YB, 65536, 1},
                  {Ta2, ALPHA, AW3T, ab3, YB, 65536, 1},
                  {Th2, Th3, HW3T, hb3, YB, YB, 1} }};
    conv128x3_k<<<dim3(8, 6, 32), 256, 0, stream>>>(d3);

    Jobs3 d4 = {{ {Th3, HY0, HW4T, hb4, YB, YB, 2},
                  {Th3, HY0, HW4T, hb4, YB, YB, 2},
                  {Th3, HY0, HW4T, hb4, YB, YB, 2} }};
    conv128x3_k<<<dim3(8, 2, 32), 256, 0, stream>>>(d4);

    // ---- persistent recurrence
    zero_bar_k<<<1, 64, 0, stream>>>(BAR);
    recur_fused_k<<<dim3(8, 32), 512, 0, stream>>>(HY0, OMEGA, ALPHA, W2,
                                                   yout, HZE, PART, BAR);

    // ---- readout
    readout_k<<<32, 256, 0, stream>>>(PART, fct, rw1, rb1, rw2, rb2, rw3, rb3, out);
}